// Round 7
// baseline (133.820 us; speedup 1.0000x reference)
//
#include <hip/hip_runtime.h>

// Fused 2-level inverse Haar DWT (UnPatcher, PATCH_SIZE=4) — double-buffered
// pipelined version (v10).
// Input  x:   [8, 256, 96, 96]  fp32
// Output out: [8, 16, 384, 384] fp32
//
// Ledger: v0 scalar 42us | v6 4xMLP 41-43 | v7 LDS+x4 ~40 (best) | v8 fat-phase
// DMA 46.8 | v9 XCD swizzle 42-44. All strictly-phased; no counter saturated.
// v10 tests the one untouched lever: intra-block load/compute overlap.
//
// Each block owns 4 consecutive 256-qp chunks of one (b,g). Two 16KB LDS
// buffers; per wave, chunk c+1's 4 global_load_lds (async DMA, 1KB/instr) are
// issued BEFORE waiting on chunk c, with counted s_waitcnt vmcnt(N) + raw
// s_barrier (no vmcnt(0) drain). FIFO arithmetic per wave:
//   iter0: FIFO [L0,L1]           -> after-L0 = 4      -> vmcnt(4)
//   iter1: FIFO [L1,S0,L2]        -> after-L1 = 8      -> vmcnt(8)
//   iter2: FIFO [S0?,L2,S1,L3]    -> after-L2 = 8      -> vmcnt(8)
//   iter3: FIFO [S2?,L3,  -  ]    -> after-L3 = 4      -> vmcnt(4)
// (stores also count in vmcnt; waiting deeper than needed never breaks
//  correctness, only overlap — these N guarantee the needed loads retired.)
//
// Compute/store identical to v7 (verified): 16 lane-consecutive LDS reads,
// 2-level +/-1 butterfly (per-level scale 2*S*S == 1), 4 float4 rows per
// thread as contiguous 1KB wave stores.

#define B_     8
#define CIN    256
#define G_     16
#define PLANE  9216   // 96*96
#define W_     96
#define OW     384
#define CHUNK  256
#define CPB    4                         // chunks per block
#define NCG    (PLANE / (CHUNK * CPB))   // 9 chunk-groups per (b,g)
#define NBLK   (B_ * G_ * NCG)           // 1152

typedef float f4 __attribute__((ext_vector_type(4)));

extern __shared__ float lds[];  // 2 buffers x 16 ch x 256 qp = 32 KB

__global__ __launch_bounds__(256) void idwt2_fused_v10(const float* __restrict__ x,
                                                       float* __restrict__ out) {
    const int bid = blockIdx.x;
    const int cg  = bid % NCG;
    const int t1  = bid / NCG;
    const int g   = t1 % G_;
    const int b   = t1 / G_;

    const int t    = threadIdx.x;
    const int w    = t >> 6;   // wave 0..3
    const int lane = t & 63;

    const float* xb = x + (size_t)b * CIN * PLANE;
    const int qpbase = cg * (CHUNK * CPB);

    // Issue wave w's 4 async 1KB DMAs for chunk c into buffer buf.
    // Global src is per-lane (+16B*lane); LDS dst is wave-uniform base, HW adds
    // lane*16B -> linear [j][qp_local] layout (v8-verified contract).
    auto issue = [&](int c, int buf) {
#pragma unroll
        for (int l = 0; l < 4; ++l) {
            const int j  = 4 * w + l;          // channel tap 0..15
            const int ch = g + 16 * j;
            const float* src = xb + (size_t)ch * PLANE + (qpbase + c * CHUNK)
                               + 4 * (size_t)lane;
            float* dst = &lds[(buf * 16 + j) * CHUNK];
            __builtin_amdgcn_global_load_lds(
                (const __attribute__((address_space(1))) void*)src,
                (__attribute__((address_space(3))) void*)dst,
                16, 0, 0);
        }
    };

    // v7-verified butterfly + store for chunk c from buffer buf.
    auto compute_store = [&](int c, int buf) {
        const float* ldsf = &lds[buf * 16 * CHUNK];
        float vv[16];
#pragma unroll
        for (int j = 0; j < 16; ++j) {
            vv[j] = ldsf[j * CHUNK + t];   // lane-consecutive -> conflict-free
        }

        float tt[4][2][2];
#pragma unroll
        for (int k = 0; k < 4; ++k) {
            float u0 = vv[k + 0] + vv[k + 4];
            float u1 = vv[k + 0] - vv[k + 4];
            float u2 = vv[k + 8] + vv[k + 12];
            float u3 = vv[k + 8] - vv[k + 12];
            tt[k][0][0] = u0 + u2;
            tt[k][0][1] = u0 - u2;
            tt[k][1][0] = u1 + u3;
            tt[k][1][1] = u1 - u3;
        }

        float rowv[4][4];
#pragma unroll
        for (int dh = 0; dh < 2; ++dh) {
#pragma unroll
            for (int dw = 0; dw < 2; ++dw) {
                float a0 = tt[0][dh][dw] + tt[1][dh][dw];
                float a1 = tt[0][dh][dw] - tt[1][dh][dw];
                float a2 = tt[2][dh][dw] + tt[3][dh][dw];
                float a3 = tt[2][dh][dw] - tt[3][dh][dw];
                rowv[2 * dh + 0][2 * dw + 0] = a0 + a2;
                rowv[2 * dh + 0][2 * dw + 1] = a0 - a2;
                rowv[2 * dh + 1][2 * dw + 0] = a1 + a3;
                rowv[2 * dh + 1][2 * dw + 1] = a1 - a3;
            }
        }

        const int qp = qpbase + c * CHUNK + t;
        const int p  = qp / W_;
        const int q  = qp % W_;
        float* obase = out + ((size_t)(b * G_ + g) * OW + 4 * (size_t)p) * OW
                       + 4 * (size_t)q;
#pragma unroll
        for (int r = 0; r < 4; ++r) {
            f4 s;
            s.x = rowv[r][0];
            s.y = rowv[r][1];
            s.z = rowv[r][2];
            s.w = rowv[r][3];
            *reinterpret_cast<f4*>(obase + (size_t)r * OW) = s;
        }
    };

    issue(0, 0);

    // ---- iter 0
    issue(1, 1);
    asm volatile("s_waitcnt vmcnt(4)" ::: "memory");
    __builtin_amdgcn_sched_barrier(0);
    __builtin_amdgcn_s_barrier();
    compute_store(0, 0);
    __builtin_amdgcn_s_barrier();

    // ---- iter 1
    issue(2, 0);
    asm volatile("s_waitcnt vmcnt(8)" ::: "memory");
    __builtin_amdgcn_sched_barrier(0);
    __builtin_amdgcn_s_barrier();
    compute_store(1, 1);
    __builtin_amdgcn_s_barrier();

    // ---- iter 2
    issue(3, 1);
    asm volatile("s_waitcnt vmcnt(8)" ::: "memory");
    __builtin_amdgcn_sched_barrier(0);
    __builtin_amdgcn_s_barrier();
    compute_store(2, 0);
    __builtin_amdgcn_s_barrier();

    // ---- iter 3 (no prefetch)
    asm volatile("s_waitcnt vmcnt(4)" ::: "memory");
    __builtin_amdgcn_sched_barrier(0);
    __builtin_amdgcn_s_barrier();
    compute_store(3, 1);
}

extern "C" void kernel_launch(void* const* d_in, const int* in_sizes, int n_in,
                              void* d_out, int out_size, void* d_ws, size_t ws_size,
                              hipStream_t stream) {
    const float* x = (const float*)d_in[0];
    float* out = (float*)d_out;
    const size_t lds_bytes = 2 * 16 * CHUNK * sizeof(float);  // 32768
    idwt2_fused_v10<<<NBLK, 256, lds_bytes, stream>>>(x, out);  // 1152 blocks
}

// Round 8
// 130.674 us; speedup vs baseline: 1.0241x; 1.0241x over previous
//
#include <hip/hip_runtime.h>

// Fused 2-level inverse Haar DWT (UnPatcher, PATCH_SIZE=4) — v7 + nontemporal
// full-line stores (v11).
// Input  x:   [8, 256, 96, 96]  fp32
// Output out: [8, 16, 384, 384] fp32
//
// Ledger (kernel-only, overhead const 86-88us): v0 42-44 | v5 49 | v6 41-43 |
// v7 39-41 (best) | v8 46.8 | v9 42-44 | v10 ~48. Levers nulled: vectorization,
// MLP, burst length, XCD swizzle, vmcnt pipelining. Unexplained counter:
// FETCH_SIZE = 36.9MB == half the input, invariant — theory: our own 75.5MB of
// cached output stores evict the fill-warmed input lines from L2/L3 mid-kernel.
// v11 = v7 with nontemporal stores. v4's nt disaster was PARTIAL-line nt
// (16B/64B lane stride -> RMW amplification); v7's stores are wave-contiguous
// 1KB = 8 full 128B lines per instruction, so nt write-around is clean.
// Guard metric: WRITE_SIZE must stay ~75.3MB. Success metric: FETCH_SIZE drops.
//
//   load:  per block, stage [16 ch][256 qp] (16KB LDS) with dwordx4 loads —
//          each instruction a contiguous 1KB wave run.
//   comp:  thread t owns qp = qp0+t; 16 lane-consecutive LDS reads
//          (conflict-free), 2-level +/-1 butterfly (per-level scale 2*S*S == 1).
//   store: 4 float4 rows per thread, contiguous 1KB wave runs, NONTEMPORAL.

#define B_     8
#define CIN    256
#define G_     16
#define PLANE  9216   // 96*96
#define W_     96
#define OW     384
#define CHUNK  256               // qp positions staged per block
#define NCHUNK (PLANE / CHUNK)   // 36
#define NBLK   (B_ * G_ * NCHUNK)  // 4608

typedef float f4 __attribute__((ext_vector_type(4)));

__global__ __launch_bounds__(256) void idwt2_fused_v11(const float* __restrict__ x,
                                                       float* __restrict__ out) {
    __shared__ f4 lds4[16][CHUNK / 4];  // [j][qp_local/4] = 16 KB

    const int bid   = blockIdx.x;
    const int chunk = bid % NCHUNK;
    const int t1    = bid / NCHUNK;
    const int g     = t1 % G_;
    const int b     = t1 / G_;
    const int qp0   = chunk * CHUNK;

    const int t    = threadIdx.x;
    const int w    = t >> 6;   // wave id 0..3
    const int lane = t & 63;

    // ---- Load phase: 4 x global_load_dwordx4 per wave, each a contiguous 1KB run.
    // Wave w loads channel-taps j = 4w..4w+3; ch = g + 16j.
    const float* xbase = x + (size_t)b * CIN * PLANE + (size_t)qp0 + 4 * (size_t)lane;
#pragma unroll
    for (int l = 0; l < 4; ++l) {
        const int j  = 4 * w + l;          // 0..15
        const int ch = g + 16 * j;
        lds4[j][lane] = *reinterpret_cast<const f4*>(xbase + (size_t)ch * PLANE);
    }
    __syncthreads();

    // ---- Compute phase: thread t owns qp = qp0 + t.
    const float* ldsf = reinterpret_cast<const float*>(lds4);
    float vv[16];
#pragma unroll
    for (int j = 0; j < 16; ++j) {
        vv[j] = ldsf[j * CHUNK + t];       // lane-consecutive -> bank-conflict-free
    }

    // Level 1 (inner butterfly): v[k][m] = vv[k + 4m]
    float tt[4][2][2];
#pragma unroll
    for (int k = 0; k < 4; ++k) {
        float u0 = vv[k + 0] + vv[k + 4];
        float u1 = vv[k + 0] - vv[k + 4];
        float u2 = vv[k + 8] + vv[k + 12];
        float u3 = vv[k + 8] - vv[k + 12];
        tt[k][0][0] = u0 + u2;
        tt[k][0][1] = u0 - u2;
        tt[k][1][0] = u1 + u3;
        tt[k][1][1] = u1 - u3;
    }

    // Level 2 (outer butterfly) -> 4x4 output tile
    float rowv[4][4];
#pragma unroll
    for (int dh = 0; dh < 2; ++dh) {
#pragma unroll
        for (int dw = 0; dw < 2; ++dw) {
            float a0 = tt[0][dh][dw] + tt[1][dh][dw];
            float a1 = tt[0][dh][dw] - tt[1][dh][dw];
            float a2 = tt[2][dh][dw] + tt[3][dh][dw];
            float a3 = tt[2][dh][dw] - tt[3][dh][dw];
            rowv[2 * dh + 0][2 * dw + 0] = a0 + a2;
            rowv[2 * dh + 0][2 * dw + 1] = a0 - a2;
            rowv[2 * dh + 1][2 * dw + 0] = a1 + a3;
            rowv[2 * dh + 1][2 * dw + 1] = a1 - a3;
        }
    }

    // ---- Store phase: 4 rows of float4; lanes have consecutive qp -> contiguous
    // 1KB wave runs (8 full 128B lines per instruction). Nontemporal: write
    // around L2/L3 so the fill-warmed INPUT lines aren't evicted by our output.
    const int qp = qp0 + t;
    const int p  = qp / W_;
    const int q  = qp % W_;
    float* obase = out + ((size_t)(b * G_ + g) * OW + 4 * (size_t)p) * OW + 4 * (size_t)q;
#pragma unroll
    for (int r = 0; r < 4; ++r) {
        f4 s;
        s.x = rowv[r][0];
        s.y = rowv[r][1];
        s.z = rowv[r][2];
        s.w = rowv[r][3];
        __builtin_nontemporal_store(s, reinterpret_cast<f4*>(obase + (size_t)r * OW));
    }
}

extern "C" void kernel_launch(void* const* d_in, const int* in_sizes, int n_in,
                              void* d_out, int out_size, void* d_ws, size_t ws_size,
                              hipStream_t stream) {
    const float* x = (const float*)d_in[0];
    float* out = (float*)d_out;
    idwt2_fused_v11<<<NBLK, 256, 0, stream>>>(x, out);  // 4608 blocks x 256 threads
}

// Round 9
// 128.421 us; speedup vs baseline: 1.0420x; 1.0175x over previous
//
#include <hip/hip_runtime.h>

// Fused 2-level inverse Haar DWT (UnPatcher, PATCH_SIZE=4) — FINAL: v7 (measured best).
// Input  x:   [8, 256, 96, 96]  fp32
// Output out: [8, 16, 384, 384] fp32
//
// Session ledger (kernel-only): v0 scalar 39-42us | v5 49 | v6 4xMLP 41-43 |
// v7 (this) ~36-40 BEST | v8 4KB-burst DMA 46.8 | v9 XCD swizzle 42-44 |
// v10 dbuf+vmcnt ~48 | v11 nt-stores ~= v7. All single-variable; every
// streaming-op lever (vectorization, MLP, LDS staging, DMA, burst length,
// stream count, XCD affinity, pipelining, nontemporal) has ~0 or negative
// derivative. Line-level traffic is ideal (WRITE_SIZE == 75.3MB, FETCH ==
// harness-determined 36.9MB, bank conflicts 0). Residual ~1.5x gap to the
// copy roofline (24us) is DRAM efficiency under ~700 concurrent mixed R/W
// streams — fixed by the problem's in/out layouts. Two sessions converge at
// ~127us total (72% of which is the harness's two 302MB L3-thrashing fills
// at 83% HBM peak).
//
//   load:  per block, stage [16 ch][256 qp] (16KB LDS) with dwordx4 loads —
//          each instruction a contiguous 1KB wave run.
//   comp:  thread t owns qp = qp0+t; 16 lane-consecutive LDS reads
//          (conflict-free), 2-level +/-1 butterfly (per-level scale 2*S*S == 1).
//   store: 4 float4 rows per thread, contiguous 1KB wave stores.

#define B_     8
#define CIN    256
#define G_     16
#define PLANE  9216   // 96*96
#define W_     96
#define OW     384
#define CHUNK  256               // qp positions staged per block
#define NCHUNK (PLANE / CHUNK)   // 36
#define NBLK   (B_ * G_ * NCHUNK)  // 4608

typedef float f4 __attribute__((ext_vector_type(4)));

__global__ __launch_bounds__(256) void idwt2_fused_v7f(const float* __restrict__ x,
                                                       float* __restrict__ out) {
    __shared__ f4 lds4[16][CHUNK / 4];  // [j][qp_local/4] = 16 KB

    const int bid   = blockIdx.x;
    const int chunk = bid % NCHUNK;
    const int t1    = bid / NCHUNK;
    const int g     = t1 % G_;
    const int b     = t1 / G_;
    const int qp0   = chunk * CHUNK;

    const int t    = threadIdx.x;
    const int w    = t >> 6;   // wave id 0..3
    const int lane = t & 63;

    // ---- Load phase: 4 x global_load_dwordx4 per wave, each a contiguous 1KB run.
    // Wave w loads channel-taps j = 4w..4w+3; ch = g + 16j.
    const float* xbase = x + (size_t)b * CIN * PLANE + (size_t)qp0 + 4 * (size_t)lane;
#pragma unroll
    for (int l = 0; l < 4; ++l) {
        const int j  = 4 * w + l;          // 0..15
        const int ch = g + 16 * j;
        lds4[j][lane] = *reinterpret_cast<const f4*>(xbase + (size_t)ch * PLANE);
    }
    __syncthreads();

    // ---- Compute phase: thread t owns qp = qp0 + t.
    const float* ldsf = reinterpret_cast<const float*>(lds4);
    float vv[16];
#pragma unroll
    for (int j = 0; j < 16; ++j) {
        vv[j] = ldsf[j * CHUNK + t];       // lane-consecutive -> bank-conflict-free
    }

    // Level 1 (inner butterfly): v[k][m] = vv[k + 4m]
    float tt[4][2][2];
#pragma unroll
    for (int k = 0; k < 4; ++k) {
        float u0 = vv[k + 0] + vv[k + 4];
        float u1 = vv[k + 0] - vv[k + 4];
        float u2 = vv[k + 8] + vv[k + 12];
        float u3 = vv[k + 8] - vv[k + 12];
        tt[k][0][0] = u0 + u2;
        tt[k][0][1] = u0 - u2;
        tt[k][1][0] = u1 + u3;
        tt[k][1][1] = u1 - u3;
    }

    // Level 2 (outer butterfly) -> 4x4 output tile
    float rowv[4][4];
#pragma unroll
    for (int dh = 0; dh < 2; ++dh) {
#pragma unroll
        for (int dw = 0; dw < 2; ++dw) {
            float a0 = tt[0][dh][dw] + tt[1][dh][dw];
            float a1 = tt[0][dh][dw] - tt[1][dh][dw];
            float a2 = tt[2][dh][dw] + tt[3][dh][dw];
            float a3 = tt[2][dh][dw] - tt[3][dh][dw];
            rowv[2 * dh + 0][2 * dw + 0] = a0 + a2;
            rowv[2 * dh + 0][2 * dw + 1] = a0 - a2;
            rowv[2 * dh + 1][2 * dw + 0] = a1 + a3;
            rowv[2 * dh + 1][2 * dw + 1] = a1 - a3;
        }
    }

    // ---- Store phase: 4 rows of float4; lanes have consecutive qp -> contiguous
    // 1KB wave stores (2 runs max at the 96-wide row wrap).
    const int qp = qp0 + t;
    const int p  = qp / W_;
    const int q  = qp % W_;
    float* obase = out + ((size_t)(b * G_ + g) * OW + 4 * (size_t)p) * OW + 4 * (size_t)q;
#pragma unroll
    for (int r = 0; r < 4; ++r) {
        f4 s;
        s.x = rowv[r][0];
        s.y = rowv[r][1];
        s.z = rowv[r][2];
        s.w = rowv[r][3];
        *reinterpret_cast<f4*>(obase + (size_t)r * OW) = s;
    }
}

extern "C" void kernel_launch(void* const* d_in, const int* in_sizes, int n_in,
                              void* d_out, int out_size, void* d_ws, size_t ws_size,
                              hipStream_t stream) {
    const float* x = (const float*)d_in[0];
    float* out = (float*)d_out;
    idwt2_fused_v7f<<<NBLK, 256, 0, stream>>>(x, out);  // 4608 blocks x 256 threads
}